// Round 11
// baseline (155.512 us; speedup 1.0000x reference)
//
#include <hip/hip_runtime.h>

#define NH 8
#define DH 64
#define SL 1024
#define NB 8
#define DIN 512
#define DOUT 512
#define PS 72  // P-tile LDS row stride in ushorts

typedef __bf16 bf16x8 __attribute__((ext_vector_type(8)));
typedef float floatx4 __attribute__((ext_vector_type(4)));
typedef unsigned short ushortx8 __attribute__((ext_vector_type(8)));

__device__ __forceinline__ unsigned short f2bf(float f) {
    unsigned int u = __builtin_bit_cast(unsigned int, f);
    u += 0x7FFFu + ((u >> 16) & 1u);
    return (unsigned short)(u >> 16);
}

__device__ __forceinline__ floatx4 mfma_bf16(bf16x8 a, bf16x8 b, floatx4 c) {
    return __builtin_amdgcn_mfma_f32_16x16x32_bf16(a, b, c, 0, 0, 0);
}

__device__ __forceinline__ void gld_lds16(const unsigned short* g, unsigned short* l) {
    __builtin_amdgcn_global_load_lds(
        (const __attribute__((address_space(1))) unsigned int*)g,
        (__attribute__((address_space(3))) unsigned int*)l, 16, 0, 0);
}

// bf16-truncate-pack two floats into one u32 (low short = bf(a), high = bf(b))
__device__ __forceinline__ unsigned int pack_bf2(float a, float b) {
    return __builtin_amdgcn_perm(__builtin_bit_cast(unsigned int, b),
                                 __builtin_bit_cast(unsigned int, a), 0x07060302u);
}

// Merged prep kernel (R18 winner, unchanged):
//  blocks [0, 6144): X fp32 -> bf16 tiled+swizzled, XCD-aligned with proj readers
//  blocks [6144, 6336): W -> transposed bf16 tiled+swizzled
__global__ __launch_bounds__(256) void prep_kernel(const float* __restrict__ Qs,
                                                   const float* __restrict__ Ks,
                                                   const float* __restrict__ Vs,
                                                   const float* __restrict__ WQ,
                                                   const float* __restrict__ WK,
                                                   const float* __restrict__ WV,
                                                   unsigned short* __restrict__ xb,
                                                   unsigned short* __restrict__ wt) {
    __shared__ unsigned short tile[64][68];
    const int bid = blockIdx.x;
    if (bid < 6144) {
        const int x = bid & 7;
        const int j = bid >> 3;               // 0..767
        const int z = j >> 8;                 // 0..2
        const int t = x * 256 + (j & 255);    // work index 0..2047
        const float* X = (z == 0) ? Qs : (z == 1 ? Ks : Vs);
        const int e = t * 256 + threadIdx.x;
        const int row = e >> 6, c = e & 63;
        const float4 a = *(const float4*)(X + e * 8);
        const float4 b = *(const float4*)(X + e * 8 + 4);
        ushortx8 o;
        o[0] = f2bf(a.x); o[1] = f2bf(a.y); o[2] = f2bf(a.z); o[3] = f2bf(a.w);
        o[4] = f2bf(b.x); o[5] = f2bf(b.y); o[6] = f2bf(b.z); o[7] = f2bf(b.w);
        const int dst = (((row >> 7) * 8 + (c >> 3)) * 128 + (row & 127)) * 64 +
                        (((c & 7) ^ (row & 7)) * 8);
        *(ushortx8*)(xb + z * 8192 * DIN + dst) = o;
    } else {
        const int b2 = bid - 6144;
        const int z = b2 >> 6;
        const int r = b2 & 63;
        const float* W = (z == 0) ? WQ : (z == 1 ? WK : WV);
        const int k0 = (r >> 3) * 64, n0 = (r & 7) * 64;
        const int tn = threadIdx.x & 63, tk = threadIdx.x >> 6;
#pragma unroll
        for (int i = 0; i < 16; ++i) {
            const int kk = tk + i * 4;
            tile[tn][kk] = f2bf(W[(k0 + kk) * DOUT + n0 + tn]);
        }
        __syncthreads();
#pragma unroll
        for (int i = 0; i < 16; ++i) {
            const int nn = tk + i * 4;
            const int n = n0 + nn, k = k0 + tn;
            const int dst = (((z * 4 + (n >> 7)) * 8 + (k >> 6)) * 128 + (n & 127)) * 64 +
                            ((((k >> 3) & 7) ^ (n & 7)) * 8) + (k & 7);
            wt[dst] = tile[nn][tn];
        }
    }
}

// m97-style GEMM, 128x128xBK64, global_load_lds staging, LDS-assembled epilogue.
// R14 T3 2-phase pipeline (best measured), unchanged.
__global__ __launch_bounds__(256) void proj_kernel(const unsigned short* __restrict__ xbt,
                                                   const unsigned short* __restrict__ wtt,
                                                   unsigned short* __restrict__ qw,
                                                   unsigned short* __restrict__ ks,
                                                   unsigned short* __restrict__ vs) {
    __shared__ __align__(16) unsigned short S[32768];  // [buf][As 8192 | Bs 8192] x2
    const int z = blockIdx.y;
    const int wg = blockIdx.x;        // 0..255
    const int ix = wg >> 3;
    const int mblk = (wg & 7) * 8 + (ix >> 2);
    const int nblk = ix & 3;
    const int w = threadIdx.x >> 6, lane = threadIdx.x & 63;
    const int l15 = lane & 15, quad = lane >> 4;
    const int wm = w >> 1, wn = w & 1;
    const int soff = lane * 8;
    const unsigned short* Ab = xbt + z * (8192 * DIN) + mblk * 8 * 8192 + (w * 4) * 512 + soff;
    const unsigned short* Bb = wtt + (z * 4 + nblk) * 8 * 8192 + (w * 4) * 512 + soff;

    floatx4 acc[4][4];
#pragma unroll
    for (int i = 0; i < 4; ++i)
#pragma unroll
        for (int j = 0; j < 4; ++j) acc[i][j] = floatx4{0.f, 0.f, 0.f, 0.f};

    auto STAGE = [&](int buf, int kblk) {
        unsigned short* Asw = &S[buf * 16384 + (w * 4) * 512];
        unsigned short* Bsw = &S[buf * 16384 + 8192 + (w * 4) * 512];
#pragma unroll
        for (int i = 0; i < 4; ++i) {
            gld_lds16(Ab + kblk * 8192 + i * 512, Asw + i * 512);
            gld_lds16(Bb + kblk * 8192 + i * 512, Bsw + i * 512);
        }
    };

    auto COMPUTE = [&](int buf) {
        const unsigned short* Asb = &S[buf * 16384];
        const unsigned short* Bsb = &S[buf * 16384 + 8192];
#pragma unroll
        for (int ksub = 0; ksub < 2; ++ksub) {
            bf16x8 af[4], bfr[4];
#pragma unroll
            for (int mi = 0; mi < 4; ++mi) {
                const int row = wm * 64 + mi * 16 + l15;
                af[mi] = *(const bf16x8*)&Asb[row * 64 + (((quad + ksub * 4) ^ (l15 & 7)) * 8)];
            }
#pragma unroll
            for (int nt = 0; nt < 4; ++nt) {
                const int row = wn * 64 + nt * 16 + l15;
                bfr[nt] = *(const bf16x8*)&Bsb[row * 64 + (((quad + ksub * 4) ^ (l15 & 7)) * 8)];
            }
#pragma unroll
            for (int mi = 0; mi < 4; ++mi)
#pragma unroll
                for (int nt = 0; nt < 4; ++nt)
                    acc[mi][nt] = mfma_bf16(af[mi], bfr[nt], acc[mi][nt]);
        }
    };

    STAGE(0, 0);
    __syncthreads();
    for (int kblk = 0; kblk < 7; ++kblk) {
        STAGE((kblk + 1) & 1, kblk + 1);
        COMPUTE(kblk & 1);
        __syncthreads();
    }
    COMPUTE(1);

    // ---- epilogue: build output-byte-exact image in LDS (aliases buf0) ----
    __syncthreads();
#pragma unroll
    for (int mi = 0; mi < 4; ++mi)
#pragma unroll
        for (int nt = 0; nt < 4; ++nt)
#pragma unroll
            for (int r = 0; r < 4; ++r) {
                const int a = wm * 64 + mi * 16 + quad * 4 + r;
                const int c = wn * 64 + nt * 16 + l15;
                const int h = c >> 6, dh = c & 63;
                float v = acc[mi][nt][r];
                int lidx;
                if (z == 0) {
                    v *= 0.18033688f;  // 0.125 * log2(e): attn uses exp2
                    lidx = h * 8192 + (a >> 4) * 1024 + (dh >> 3) * 128 + (a & 15) * 8 + (dh & 7);
                } else if (z == 1) {
                    lidx = (((((h << 3) + (a >> 4)) << 1) | (dh >> 5))) * 512 +
                           (a & 15) * 32 + (dh & 31);
                } else {
                    const int s64 = ((a & 15) << 2) | ((a >> 4) & 3);
                    lidx = ((((h << 1) | (a >> 6)) << 1) | (s64 >> 5)) * 2048 +
                           dh * 32 + (s64 & 31);
                }
                S[lidx] = f2bf(v);
            }
    __syncthreads();

    const int b = mblk >> 3;
    const int li0 = (mblk & 7) * 128;
    const int tid = threadIdx.x;
    unsigned short* outp = (z == 0) ? qw : (z == 1 ? ks : vs);
#pragma unroll
    for (int j = 0; j < 8; ++j) {
        const int off = j * 2048 + tid * 8;
        const ushortx8 val = *(const ushortx8*)(S + off);
        int gidx;
        if (z == 0) {
            const int h = off >> 13, o13 = off & 8191;
            gidx = ((b * 8 + nblk * 2 + h) * 64 + (li0 >> 4) + (o13 >> 10)) * 1024 + (o13 & 1023);
        } else if (z == 1) {
            const int region = off >> 9, pos = off & 511;
            const int h = region >> 4, g = (region >> 1) & 7, d5 = region & 1;
            gidx = (((b * 8 + nblk * 2 + h) * 64 + (li0 >> 4) + g) * 2 + d5) * 512 + pos;
        } else {
            const int region = off >> 11, pos = off & 2047;
            const int h = region >> 2, l6 = (region >> 1) & 1, s5 = region & 1;
            gidx = ((b * 8 + nblk * 2 + h) * 32 + (li0 >> 5) + l6 * 2 + s5) * 2048 + pos;
        }
        *(ushortx8*)(outp + gidx) = val;
    }
}

// One K-frame (64 keys) for a 64-row q-group (4 tiles A..D sharing K/V).
// R19: M=64 per wave. QK in two tile-pair groups reusing s/u regs (caps VGPR);
// V issued after last K use; PV for all 4 tiles with shared V frags.
// Masked frame (DOMASK) has kt==m0 structurally: slice sets A:t=0, B:t<=1,
// C:t<=2, D:all; element masks zero the rest (skipped slices stay zf->exp2=1
// but key>row always holds for them).
template <bool DOMASK>
__device__ __forceinline__ void frame64(
    int kt, int m0, int l15, int quad,
    const unsigned short* __restrict__ ksb,
    const unsigned short* __restrict__ vsb,
    unsigned short* myPs,
    bf16x8 QA0, bf16x8 QA1, bf16x8 QB0, bf16x8 QB1,
    bf16x8 QC0, bf16x8 QC1, bf16x8 QD0, bf16x8 QD1,
    floatx4& oA0, floatx4& oA1, floatx4& oA2, floatx4& oA3,
    floatx4& oB0, floatx4& oB1, floatx4& oB2, floatx4& oB3,
    floatx4& oC0, floatx4& oC1, floatx4& oC2, floatx4& oC3,
    floatx4& oD0, floatx4& oD1, floatx4& oD2, floatx4& oD3,
    float& lA0, float& lA1, float& lA2, float& lA3,
    float& lB0, float& lB1, float& lB2, float& lB3,
    float& lC0, float& lC1, float& lC2, float& lC3,
    float& lD0, float& lD1, float& lD2, float& lD3) {
    const floatx4 zf = {0.f, 0.f, 0.f, 0.f};
    const unsigned short* kp = ksb + (kt >> 4) * 1024;
    const bf16x8 k00 = *(const bf16x8*)(kp);
    const bf16x8 k01 = *(const bf16x8*)(kp + 512);
    const bf16x8 k10 = *(const bf16x8*)(kp + 1024);
    const bf16x8 k11 = *(const bf16x8*)(kp + 1536);
    const bf16x8 k20 = *(const bf16x8*)(kp + 2048);
    const bf16x8 k21 = *(const bf16x8*)(kp + 2560);
    const bf16x8 k30 = *(const bf16x8*)(kp + 3072);
    const bf16x8 k31 = *(const bf16x8*)(kp + 3584);

    // ---- QK group 1: tiles A (s) and B (u) ----
    floatx4 s0 = zf, s1 = zf, s2 = zf, s3 = zf;
    floatx4 u0 = zf, u1 = zf, u2 = zf, u3 = zf;
    __builtin_amdgcn_s_setprio(1);
    s0 = mfma_bf16(QA1, k01, mfma_bf16(QA0, k00, zf));
    u0 = mfma_bf16(QB1, k01, mfma_bf16(QB0, k00, zf));
    u1 = mfma_bf16(QB1, k11, mfma_bf16(QB0, k10, zf));
    if (!DOMASK) {
        s1 = mfma_bf16(QA1, k11, mfma_bf16(QA0, k10, zf));
        s2 = mfma_bf16(QA1, k21, mfma_bf16(QA0, k20, zf));
        s3 = mfma_bf16(QA1, k31, mfma_bf16(QA0, k30, zf));
        u2 = mfma_bf16(QB1, k21, mfma_bf16(QB0, k20, zf));
        u3 = mfma_bf16(QB1, k31, mfma_bf16(QB0, k30, zf));
    }
    __builtin_amdgcn_s_setprio(0);

#define SMTAIL_R(R, S0, S1, S2, S3, TOFF, LACC)                              \
    {                                                                        \
        const int rowq = m0 + (TOFF) + quad * 4 + R;                         \
        float p0 = __builtin_amdgcn_exp2f(S0[R]);                            \
        float p1 = __builtin_amdgcn_exp2f(S1[R]);                            \
        float p2 = __builtin_amdgcn_exp2f(S2[R]);                            \
        float p3 = __builtin_amdgcn_exp2f(S3[R]);                            \
        if (DOMASK) {                                                        \
            if (kt + l15 > rowq) p0 = 0.f;                                   \
            if (kt + 16 + l15 > rowq) p1 = 0.f;                              \
            if (kt + 32 + l15 > rowq) p2 = 0.f;                              \
            if (kt + 48 + l15 > rowq) p3 = 0.f;                              \
        }                                                                    \
        LACC += (p0 + p1) + (p2 + p3);                                       \
        uint2 pk;                                                            \
        pk.x = pack_bf2(p0, p1);                                             \
        pk.y = pack_bf2(p2, p3);                                             \
        *(uint2*)(myPs + ((TOFF) + quad * 4 + R) * PS + l15 * 4) = pk;       \
    }
    SMTAIL_R(0, s0, s1, s2, s3, 0, lA0)
    SMTAIL_R(1, s0, s1, s2, s3, 0, lA1)
    SMTAIL_R(2, s0, s1, s2, s3, 0, lA2)
    SMTAIL_R(3, s0, s1, s2, s3, 0, lA3)
    SMTAIL_R(0, u0, u1, u2, u3, 16, lB0)
    SMTAIL_R(1, u0, u1, u2, u3, 16, lB1)
    SMTAIL_R(2, u0, u1, u2, u3, 16, lB2)
    SMTAIL_R(3, u0, u1, u2, u3, 16, lB3)

    // ---- QK group 2: tiles C (s) and D (u); K regs die here ----
    __builtin_amdgcn_s_setprio(1);
    s0 = mfma_bf16(QC1, k01, mfma_bf16(QC0, k00, zf));
    s1 = mfma_bf16(QC1, k11, mfma_bf16(QC0, k10, zf));
    s2 = mfma_bf16(QC1, k21, mfma_bf16(QC0, k20, zf));
    u0 = mfma_bf16(QD1, k01, mfma_bf16(QD0, k00, zf));
    u1 = mfma_bf16(QD1, k11, mfma_bf16(QD0, k10, zf));
    u2 = mfma_bf16(QD1, k21, mfma_bf16(QD0, k20, zf));
    u3 = mfma_bf16(QD1, k31, mfma_bf16(QD0, k30, zf));
    if (!DOMASK) {
        s3 = mfma_bf16(QC1, k31, mfma_bf16(QC0, k30, zf));
    } else {
        s3 = zf;  // group-1 may not have left it zero in future edits; explicit
    }
    __builtin_amdgcn_s_setprio(0);

    // V after last K use: vmcnt in-order; latency hides under smTAIL C,D.
    const unsigned short* vb = vsb + (kt >> 5) * 2048;
    const bf16x8 v00 = *(const bf16x8*)(vb);
    const bf16x8 v01 = *(const bf16x8*)(vb + 512);
    const bf16x8 v02 = *(const bf16x8*)(vb + 1024);
    const bf16x8 v03 = *(const bf16x8*)(vb + 1536);
    const bf16x8 v10 = *(const bf16x8*)(vb + 2048);
    const bf16x8 v11 = *(const bf16x8*)(vb + 2560);
    const bf16x8 v12 = *(const bf16x8*)(vb + 3072);
    const bf16x8 v13 = *(const bf16x8*)(vb + 3584);

    SMTAIL_R(0, s0, s1, s2, s3, 32, lC0)
    SMTAIL_R(1, s0, s1, s2, s3, 32, lC1)
    SMTAIL_R(2, s0, s1, s2, s3, 32, lC2)
    SMTAIL_R(3, s0, s1, s2, s3, 32, lC3)
    SMTAIL_R(0, u0, u1, u2, u3, 48, lD0)
    SMTAIL_R(1, u0, u1, u2, u3, 48, lD1)
    SMTAIL_R(2, u0, u1, u2, u3, 48, lD2)
    SMTAIL_R(3, u0, u1, u2, u3, 48, lD3)
#undef SMTAIL_R

    __builtin_amdgcn_wave_barrier();
    const bf16x8 PA0 = *(const bf16x8*)(myPs + l15 * PS + quad * 8);
    const bf16x8 PA1 = *(const bf16x8*)(myPs + l15 * PS + 32 + quad * 8);
    const bf16x8 PB0 = *(const bf16x8*)(myPs + (16 + l15) * PS + quad * 8);
    const bf16x8 PB1 = *(const bf16x8*)(myPs + (16 + l15) * PS + 32 + quad * 8);
    const bf16x8 PC0 = *(const bf16x8*)(myPs + (32 + l15) * PS + quad * 8);
    const bf16x8 PC1 = *(const bf16x8*)(myPs + (32 + l15) * PS + 32 + quad * 8);
    const bf16x8 PD0 = *(const bf16x8*)(myPs + (48 + l15) * PS + quad * 8);
    const bf16x8 PD1 = *(const bf16x8*)(myPs + (48 + l15) * PS + 32 + quad * 8);
    __builtin_amdgcn_wave_barrier();
    __builtin_amdgcn_s_setprio(1);
    oA0 = mfma_bf16(PA1, v10, mfma_bf16(PA0, v00, oA0));
    oA1 = mfma_bf16(PA1, v11, mfma_bf16(PA0, v01, oA1));
    oA2 = mfma_bf16(PA1, v12, mfma_bf16(PA0, v02, oA2));
    oA3 = mfma_bf16(PA1, v13, mfma_bf16(PA0, v03, oA3));
    oB0 = mfma_bf16(PB1, v10, mfma_bf16(PB0, v00, oB0));
    oB1 = mfma_bf16(PB1, v11, mfma_bf16(PB0, v01, oB1));
    oB2 = mfma_bf16(PB1, v12, mfma_bf16(PB0, v02, oB2));
    oB3 = mfma_bf16(PB1, v13, mfma_bf16(PB0, v03, oB3));
    oC0 = mfma_bf16(PC1, v10, mfma_bf16(PC0, v00, oC0));
    oC1 = mfma_bf16(PC1, v11, mfma_bf16(PC0, v01, oC1));
    oC2 = mfma_bf16(PC1, v12, mfma_bf16(PC0, v02, oC2));
    oC3 = mfma_bf16(PC1, v13, mfma_bf16(PC0, v03, oC3));
    oD0 = mfma_bf16(PD1, v10, mfma_bf16(PD0, v00, oD0));
    oD1 = mfma_bf16(PD1, v11, mfma_bf16(PD0, v01, oD1));
    oD2 = mfma_bf16(PD1, v12, mfma_bf16(PD0, v02, oD2));
    oD3 = mfma_bf16(PD1, v13, mfma_bf16(PD0, v03, oD3));
    __builtin_amdgcn_s_setprio(0);
}

// Causal flash attention, split-K, M=64 per wave (R19).
// Block: waves {0,1} = 64-row group gp (split-K halves), waves {2,3} =
// complementary group 15-gp (constant block work). Grid 512, XCD bh-locality.
__global__ __launch_bounds__(256) void attn_kernel(const unsigned short* __restrict__ qw,
                                                   const unsigned short* __restrict__ ksp,
                                                   const unsigned short* __restrict__ vsp,
                                                   float* __restrict__ out) {
    __shared__ union {
        unsigned short Ps[4][64 * PS];
        float Cb[2][64][84];
    } sh;
    const int w = threadIdx.x >> 6;
    const int lane = threadIdx.x & 63;
    const int l15 = lane & 15, quad = lane >> 4;
    // XCD-locality decode: dispatch slot s -> XCD s&7 (round-robin model).
    const int s_ = blockIdx.x;               // 0..511
    const int xcd = s_ & 7;
    const int idx = s_ >> 3;                 // 0..63
    const int bh = xcd * 8 + (idx & 7);      // XCD i serves heads 8i..8i+7
    const int g8 = idx >> 3;                 // 0..7
    const int b = bh >> 3, h = bh & 7;
    const int gp = (w < 2) ? g8 : 15 - g8;   // 64-row group 0..15
    const int half = w & 1;
    const int m0 = gp * 64;

    // Q fragments for 4 tiles (tile index 4*gp + T)
    const unsigned short* qp = qw + (bh * 64 + 4 * gp) * 1024 + quad * 128 + l15 * 8;
    const bf16x8 QA0 = *(const bf16x8*)qp;
    const bf16x8 QA1 = *(const bf16x8*)(qp + 512);
    const bf16x8 QB0 = *(const bf16x8*)(qp + 1024);
    const bf16x8 QB1 = *(const bf16x8*)(qp + 1536);
    const bf16x8 QC0 = *(const bf16x8*)(qp + 2048);
    const bf16x8 QC1 = *(const bf16x8*)(qp + 2560);
    const bf16x8 QD0 = *(const bf16x8*)(qp + 3072);
    const bf16x8 QD1 = *(const bf16x8*)(qp + 3584);

    const unsigned short* ksb = ksp + (bh * 64) * 2 * 512 + l15 * 32 + quad * 8;
    const unsigned short* vsb = vsp + (bh * 32 * 64 + l15) * 32 + quad * 8;
    unsigned short* myPs = sh.Ps[w];

    const floatx4 zf = {0.f, 0.f, 0.f, 0.f};
    floatx4 oA0 = zf, oA1 = zf, oA2 = zf, oA3 = zf;
    floatx4 oB0 = zf, oB1 = zf, oB2 = zf, oB3 = zf;
    floatx4 oC0 = zf, oC1 = zf, oC2 = zf, oC3 = zf;
    floatx4 oD0 = zf, oD1 = zf, oD2 = zf, oD3 = zf;
    float lA0 = 0.f, lA1 = 0.f, lA2 = 0.f, lA3 = 0.f;
    float lB0 = 0.f, lB1 = 0.f, lB2 = 0.f, lB3 = 0.f;
    float lC0 = 0.f, lC1 = 0.f, lC2 = 0.f, lC3 = 0.f;
    float lD0 = 0.f, lD1 = 0.f, lD2 = 0.f, lD3 = 0.f;

    // frames covering keys 0 .. m0+63 (tile D's diagonal); last = gp is masked
    const int last = gp;
    for (int j = half; j < last; j += 2)
        frame64<false>(j * 64, m0, l15, quad, ksb, vsb, myPs,
                       QA0, QA1, QB0, QB1, QC0, QC1, QD0, QD1,
                       oA0, oA1, oA2, oA3, oB0, oB1, oB2, oB3,
                       oC0, oC1, oC2, oC3, oD0, oD1, oD2, oD3,
                       lA0, lA1, lA2, lA3, lB0, lB1, lB2, lB3,
                       lC0, lC1, lC2, lC3, lD0, lD1, lD2, lD3);
    if ((last & 1) == half)
        frame64<true>(last * 64, m0, l15, quad, ksb, vsb, myPs,
                      QA0, QA1, QB0, QB1, QC0, QC1, QD0, QD1,
                      oA0, oA1, oA2, oA3, oB0, oB1, oB2, oB3,
                      oC0, oC1, oC2, oC3, oD0, oD1, oD2, oD3,
                      lA0, lA1, lA2, lA3, lB0, lB1, lB2, lB3,
                      lC0, lC1, lC2, lC3, lD0, lD1, lD2, lD3);

    // combine split-K partners via LDS (pure addition; union with Ps -> barrier first)
    __syncthreads();
    if (half == 1) {
        float* cb = &sh.Cb[w >> 1][lane][0];
#define ST4(BASE, O) { cb[BASE] = O[0]; cb[BASE + 1] = O[1]; cb[BASE + 2] = O[2]; cb[BASE + 3] = O[3]; }
        ST4(0, oA0)  ST4(4, oA1)  ST4(8, oA2)  ST4(12, oA3)
        ST4(16, oB0) ST4(20, oB1) ST4(24, oB2) ST4(28, oB3)
        ST4(32, oC0) ST4(36, oC1) ST4(40, oC2) ST4(44, oC3)
        ST4(48, oD0) ST4(52, oD1) ST4(56, oD2) ST4(60, oD3)
#undef ST4
        cb[64] = lA0; cb[65] = lA1; cb[66] = lA2; cb[67] = lA3;
        cb[68] = lB0; cb[69] = lB1; cb[70] = lB2; cb[71] = lB3;
        cb[72] = lC0; cb[73] = lC1; cb[74] = lC2; cb[75] = lC3;
        cb[76] = lD0; cb[77] = lD1; cb[78] = lD2; cb[79] = lD3;
    }
    __syncthreads();
    if (half == 0) {
        const float* cb = &sh.Cb[w >> 1][lane][0];
#define AD4(BASE, O) { O[0] += cb[BASE]; O[1] += cb[BASE + 1]; O[2] += cb[BASE + 2]; O[3] += cb[BASE + 3]; }
        AD4(0, oA0)  AD4(4, oA1)  AD4(8, oA2)  AD4(12, oA3)
        AD4(16, oB0) AD4(20, oB1) AD4(24, oB2) AD4(28, oB3)
        AD4(32, oC0) AD4(36, oC1) AD4(40, oC2) AD4(44, oC3)
        AD4(48, oD0) AD4(52, oD1) AD4(56, oD2) AD4(60, oD3)
#undef AD4
        lA0 += cb[64]; lA1 += cb[65]; lA2 += cb[66]; lA3 += cb[67];
        lB0 += cb[68]; lB1 += cb[69]; lB2 += cb[70]; lB3 += cb[71];
        lC0 += cb[72]; lC1 += cb[73]; lC2 += cb[74]; lC3 += cb[75];
        lD0 += cb[76]; lD1 += cb[77]; lD2 += cb[78]; lD3 += cb[79];
#define OUT_TR(R, TOFF, O0, O1, O2, O3, LR)                                   \
    {                                                                         \
        float lr = LR;                                                        \
        lr += __shfl_xor(lr, 1);                                              \
        lr += __shfl_xor(lr, 2);                                              \
        lr += __shfl_xor(lr, 4);                                              \
        lr += __shfl_xor(lr, 8);                                              \
        const float inv = 1.0f / lr;                                          \
        const int rowq = m0 + (TOFF) + quad * 4 + R;                          \
        float* op = out + (b * SL + rowq) * DOUT + h * DH + l15;              \
        op[0] = O0[R] * inv;  op[16] = O1[R] * inv;                           \
        op[32] = O2[R] * inv; op[48] = O3[R] * inv;                           \
    }
        OUT_TR(0, 0, oA0, oA1, oA2, oA3, lA0)
        OUT_TR(1, 0, oA0, oA1, oA2, oA3, lA1)
        OUT_TR(2, 0, oA0, oA1, oA2, oA3, lA2)
        OUT_TR(3, 0, oA0, oA1, oA2, oA3, lA3)
        OUT_TR(0, 16, oB0, oB1, oB2, oB3, lB0)
        OUT_TR(1, 16, oB0, oB1, oB2, oB3, lB1)
        OUT_TR(2, 16, oB0, oB1, oB2, oB3, lB2)
        OUT_TR(3, 16, oB0, oB1, oB2, oB3, lB3)
        OUT_TR(0, 32, oC0, oC1, oC2, oC3, lC0)
        OUT_TR(1, 32, oC0, oC1, oC2, oC3, lC1)
        OUT_TR(2, 32, oC0, oC1, oC2, oC3, lC2)
        OUT_TR(3, 32, oC0, oC1, oC2, oC3, lC3)
        OUT_TR(0, 48, oD0, oD1, oD2, oD3, lD0)
        OUT_TR(1, 48, oD0, oD1, oD2, oD3, lD1)
        OUT_TR(2, 48, oD0, oD1, oD2, oD3, lD2)
        OUT_TR(3, 48, oD0, oD1, oD2, oD3, lD3)
#undef OUT_TR
    }
}

extern "C" void kernel_launch(void* const* d_in, const int* in_sizes, int n_in,
                              void* d_out, int out_size, void* d_ws, size_t ws_size,
                              hipStream_t stream) {
    const float* Qs = (const float*)d_in[0];
    const float* Ks = (const float*)d_in[1];
    const float* Vs = (const float*)d_in[2];
    const float* WQ = (const float*)d_in[3];
    const float* WK = (const float*)d_in[4];
    const float* WV = (const float*)d_in[5];
    float* out = (float*)d_out;

    unsigned short* xb = (unsigned short*)d_ws;          // 3*8192*512 (tiled+swz)
    unsigned short* wt = xb + 3 * 8192 * DIN;            // 3*512*512 (tiled+swz)
    unsigned short* qw = wt + 3 * DIN * DOUT;            // frag-blocked, pre-scaled
    unsigned short* ks = qw + NB * NH * SL * DH;         // blocked
    unsigned short* vs = ks + NB * NH * SL * DH;         // blocked+permuted

    prep_kernel<<<dim3(6336), 256, 0, stream>>>(Qs, Ks, Vs, WQ, WK, WV, xb, wt);
    proj_kernel<<<dim3(256, 3), 256, 0, stream>>>(xb, wt, qw, ks, vs);
    attn_kernel<<<dim3(512), 256, 0, stream>>>(qw, ks, vs, out);
}